// Round 9
// baseline (454.973 us; speedup 1.0000x reference)
//
#include <hip/hip_runtime.h>
#include <stdint.h>

// Problem constants
#define B_    8
#define T_    512
#define V_    2048
#define H_    4
#define NE_   768
#define D_    8192      // V_*H_
#define PWROW 32768     // V_*H_*H_
#define M1    3072      // NE_*H_
#define K3    2048      // T_*H_
#define MTT_E 6291456UL // NE_*D_

#define AS1 __attribute__((address_space(1)))
#define AS3 __attribute__((address_space(3)))

typedef __attribute__((ext_vector_type(8))) short bf16x8;
typedef __attribute__((ext_vector_type(4))) float f32x4;

__device__ __forceinline__ unsigned short f2bf(float f) {
  union { float f; unsigned int u; } c; c.f = f;
  unsigned int u = c.u;
  return (unsigned short)((u + 0x7FFFu + ((u >> 16) & 1u)) >> 16);
}
__device__ __forceinline__ float bf2f(unsigned short s) {
  union { unsigned int u; float f; } c; c.u = ((unsigned int)s) << 16;
  return c.f;
}
__device__ __forceinline__ unsigned int pk2(float a, float b) {
  return (unsigned int)f2bf(a) | ((unsigned int)f2bf(b) << 16);
}

// ---------------------------------------------------------------------------
// fp32 -> bf16 elementwise convert (B / cooc only now)
// ---------------------------------------------------------------------------
__global__ __launch_bounds__(256) void cvt_k(
    const float* __restrict__ src, unsigned short* __restrict__ dst, int n4) {
  int i = blockIdx.x * 256 + threadIdx.x;
  const int stride = gridDim.x * 256;
  for (; i < n4; i += stride) {
    const float4 v = ((const float4*)src)[i];
    ushort4 o;
    o.x = f2bf(v.x); o.y = f2bf(v.y); o.z = f2bf(v.z); o.w = f2bf(v.w);
    ((ushort4*)dst)[i] = o;
  }
}

// ---------------------------------------------------------------------------
// Kernel 1 (pipelined 256x256, A-cvt fused): C[m][t] over K-slice z.
// 8 waves (2M x 4N), BK=64, 128KB LDS double-buffer, chunk-XOR swizzle.
// B: global_load_lds 16B from pre-converted Bq (issued at tile top).
// A: fp32 reg-staged from pw directly (T14): 8x dwordx4 issued between the
//    two MFMA half-clusters, vmcnt(0) after compute, cvt -> 4x ds_write_b128
//    to swizzled chunks. One barrier per tile (drain covers both buffers).
// Output: partial z in mtT scatter layout [e][t*4+h], bf16 ushort4 stores.
// ---------------------------------------------------------------------------
__global__ __launch_bounds__(512, 2) void gemm1pA_k(
    const float* __restrict__ A32,          // pw viewed [3072][8192] fp32
    const unsigned short* __restrict__ Bq,  // [2048][8192] bf16
    unsigned short* __restrict__ P,         // partials, z-strided by MTT_E
    int kk_per) {
  __shared__ unsigned short lds[2][2][256 * 64];   // [dbuf][A=0/B=1] 128 KB
  const int r0 = blockIdx.x * 256;   // m
  const int t0 = blockIdx.y * 256;   // t
  const int z  = blockIdx.z;
  const int kbeg = z * kk_per;
  const int NT = kk_per / 64;
  const int tid  = threadIdx.x;
  const int lane = tid & 63, w = tid >> 6;
  const int wm = w >> 2, wn = w & 3;
  const int fr = lane & 15, fq = lane >> 4;
  unsigned short* __restrict__ Pz = P + (size_t)z * MTT_E;

  f32x4 acc[8][4];
  #pragma unroll
  for (int m = 0; m < 8; ++m)
    #pragma unroll
    for (int n = 0; n < 4; ++n) acc[m][n] = (f32x4){0.f, 0.f, 0.f, 0.f};

  // B staging: phys chunk q holds logical col16 c=(q&7)^(row&7), row=q>>3.
  auto STAGE_B = [&](int d, int k0) {
    #pragma unroll
    for (int i = 0; i < 4; ++i) {
      const int q   = (w * 4 + i) * 64 + lane;
      const int row = q >> 3;
      const int c16 = (q & 7) ^ (row & 7);
      __builtin_amdgcn_global_load_lds(
          (const AS1 void*)(Bq + (size_t)(t0 + row) * D_ + k0 + c16 * 8),
          (AS3 void*)(&lds[d][1][(w * 4 + i) * 512]), 16, 0, 0);
    }
  };
  // A fp32 load into regs: thread handles logical chunks q = i*512+tid
  // (8 fp32 = 32B = 2 dwordx4, coalesced per wave).
  float4 ga[8];
  auto LOAD_A = [&](int k0) {
    #pragma unroll
    for (int i = 0; i < 4; ++i) {
      const int q = i * 512 + tid;
      const int row = q >> 3, c = q & 7;
      const float* src = A32 + (size_t)(r0 + row) * D_ + k0 + c * 8;
      ga[2 * i]     = *(const float4*)(src);
      ga[2 * i + 1] = *(const float4*)(src + 4);
    }
  };
  auto WRITE_A = [&](int d) {
    #pragma unroll
    for (int i = 0; i < 4; ++i) {
      const int q = i * 512 + tid;
      const int row = q >> 3, c = q & 7;
      const int pc = c ^ (row & 7);
      int4 o;
      o.x = (int)pk2(ga[2 * i].x,     ga[2 * i].y);
      o.y = (int)pk2(ga[2 * i].z,     ga[2 * i].w);
      o.z = (int)pk2(ga[2 * i + 1].x, ga[2 * i + 1].y);
      o.w = (int)pk2(ga[2 * i + 1].z, ga[2 * i + 1].w);
      *(int4*)&lds[d][0][row * 64 + pc * 8] = o;
    }
  };
  // swizzled ushort offset of logical (row, col16)
  #define OFFS(r, c) ((r) * 64 + (((c) ^ ((r) & 7)) * 8))

  // Prologue: full tile 0
  STAGE_B(0, kbeg);
  LOAD_A(kbeg);
  asm volatile("s_waitcnt vmcnt(0)" ::: "memory");
  WRITE_A(0);
  asm volatile("s_waitcnt lgkmcnt(0)" ::: "memory");
  __builtin_amdgcn_sched_barrier(0);
  __builtin_amdgcn_s_barrier();
  __builtin_amdgcn_sched_barrier(0);

  for (int kt = 0; kt < NT; ++kt) {
    const int cur = kt & 1, nxt = cur ^ 1;
    const bool hasnext = (kt + 1 < NT);
    const int kn = kbeg + (kt + 1) * 64;

    if (hasnext) STAGE_B(nxt, kn);

    const unsigned short* Ab = &lds[cur][0][0];
    const unsigned short* Bb = &lds[cur][1][0];

    bf16x8 afA[4][2], afB[4][2], bf0[2][2], bf1[2][2];
    #pragma unroll
    for (int m = 0; m < 4; ++m)
      #pragma unroll
      for (int kk = 0; kk < 2; ++kk)
        afA[m][kk] = *(const bf16x8*)&Ab[OFFS(wm * 128 + m * 16 + fr, kk * 4 + fq)];
    #pragma unroll
    for (int n = 0; n < 2; ++n)
      #pragma unroll
      for (int kk = 0; kk < 2; ++kk) {
        bf0[n][kk] = *(const bf16x8*)&Bb[OFFS(wn * 64 + n * 16 + fr, kk * 4 + fq)];
        bf1[n][kk] = *(const bf16x8*)&Bb[OFFS(wn * 64 + 32 + n * 16 + fr, kk * 4 + fq)];
      }

    __builtin_amdgcn_s_setprio(1);
    #pragma unroll
    for (int m = 0; m < 4; ++m)
      #pragma unroll
      for (int n = 0; n < 2; ++n)
        #pragma unroll
        for (int kk = 0; kk < 2; ++kk) {
          acc[m][n]     = __builtin_amdgcn_mfma_f32_16x16x32_bf16(afA[m][kk], bf0[n][kk], acc[m][n], 0, 0, 0);
          acc[m][n + 2] = __builtin_amdgcn_mfma_f32_16x16x32_bf16(afA[m][kk], bf1[n][kk], acc[m][n + 2], 0, 0, 0);
        }
    __builtin_amdgcn_s_setprio(0);

    if (hasnext) LOAD_A(kn);   // issue fp32 A loads; land under MFMA half 2

    #pragma unroll
    for (int m = 0; m < 4; ++m)
      #pragma unroll
      for (int kk = 0; kk < 2; ++kk)
        afB[m][kk] = *(const bf16x8*)&Ab[OFFS(wm * 128 + 64 + m * 16 + fr, kk * 4 + fq)];

    __builtin_amdgcn_s_setprio(1);
    #pragma unroll
    for (int m = 0; m < 4; ++m)
      #pragma unroll
      for (int n = 0; n < 2; ++n)
        #pragma unroll
        for (int kk = 0; kk < 2; ++kk) {
          acc[m + 4][n]     = __builtin_amdgcn_mfma_f32_16x16x32_bf16(afB[m][kk], bf0[n][kk], acc[m + 4][n], 0, 0, 0);
          acc[m + 4][n + 2] = __builtin_amdgcn_mfma_f32_16x16x32_bf16(afB[m][kk], bf1[n][kk], acc[m + 4][n + 2], 0, 0, 0);
        }
    __builtin_amdgcn_s_setprio(0);

    if (hasnext) {
      asm volatile("s_waitcnt vmcnt(0)" ::: "memory");  // A regs + B gloads landed
      WRITE_A(nxt);
    }
    asm volatile("s_waitcnt lgkmcnt(0)" ::: "memory");  // reads + writes drained
    __builtin_amdgcn_sched_barrier(0);
    __builtin_amdgcn_s_barrier();
    __builtin_amdgcn_sched_barrier(0);
  }
  #undef OFFS

  // Epilogue: rows rbase..rbase+3 (rbase%4==0) -> one ushort4 at
  // Pz[(rbase>>2)*D_ + t*4].
  #pragma unroll
  for (int m = 0; m < 8; ++m)
    #pragma unroll
    for (int n = 0; n < 4; ++n) {
      const int rbase = r0 + wm * 128 + m * 16 + fq * 4;
      const int t = t0 + wn * 64 + n * 16 + fr;
      ushort4 o;
      o.x = f2bf(acc[m][n][0]); o.y = f2bf(acc[m][n][1]);
      o.z = f2bf(acc[m][n][2]); o.w = f2bf(acc[m][n][3]);
      *(ushort4*)&Pz[(size_t)(rbase >> 2) * D_ + t * H_] = o;
    }
}

// ---------------------------------------------------------------------------
// Fused reduce+gather, LDS-staged (proven round-8):
// per block (one e-row): stream-sum nz partials coalesced into a 16KB LDS
// row (fp32 sum, bf16 round), then gather 8B chunks into GT.
// ---------------------------------------------------------------------------
__global__ __launch_bounds__(256) void rgather_k(
    const unsigned short* __restrict__ P, const int* __restrict__ x,
    unsigned short* __restrict__ GT, int nz) {
  __shared__ int toks[B_ * T_];          // 16 KB
  __shared__ unsigned short row[D_];     // 16 KB
  const int tid = threadIdx.x;
  #pragma unroll
  for (int c = 0; c < 16; ++c) toks[c * 256 + tid] = x[c * 256 + tid];

  const int e = blockIdx.x;
  const unsigned short* prow = P + (size_t)e * D_;

  float s[8][4];
  #pragma unroll
  for (int i = 0; i < 8; ++i) { s[i][0] = s[i][1] = s[i][2] = s[i][3] = 0.f; }
  for (int z = 0; z < nz; ++z) {
    const unsigned short* pz = prow + (size_t)z * MTT_E;
    #pragma unroll
    for (int i = 0; i < 8; ++i) {
      const ushort4 v = *(const ushort4*)(pz + (size_t)(i * 256 + tid) * 4);
      s[i][0] += bf2f(v.x); s[i][1] += bf2f(v.y);
      s[i][2] += bf2f(v.z); s[i][3] += bf2f(v.w);
    }
  }
  #pragma unroll
  for (int i = 0; i < 8; ++i) {
    ushort4 o;
    o.x = f2bf(s[i][0]); o.y = f2bf(s[i][1]);
    o.z = f2bf(s[i][2]); o.w = f2bf(s[i][3]);
    *(ushort4*)&row[(i * 256 + tid) * 4] = o;
  }
  __syncthreads();

  const int lane = tid & 63, wave = tid >> 6;
  #pragma unroll
  for (int bb = 0; bb < 2; ++bb) {
    const int b = wave * 2 + bb;
    unsigned short* grow = GT + ((size_t)b * NE_ + e) * K3;
    const int* tb = toks + b * T_;
    #pragma unroll
    for (int r = 0; r < 8; ++r) {
      const int j = r * 64 + lane;
      const uint2 v = *(const uint2*)&row[tb[j] * H_];
      *(uint2*)(grow + j * H_) = v;
    }
  }
}

// ---------------------------------------------------------------------------
// Kernel 3 (dense): y[b][i][e] = sum_k att[b,i,k] * GT[b,e,k] + pb[e]
// ---------------------------------------------------------------------------
__global__ __launch_bounds__(256) void gemm3f_k(
    const unsigned short* __restrict__ att,
    const unsigned short* __restrict__ GT,
    const float* __restrict__ bias,
    float* __restrict__ y) {
  __shared__ unsigned short As[128 * 32];
  __shared__ unsigned short Bs[64 * 32];
  const int b  = blockIdx.z;
  const int i0 = blockIdx.x * 128;
  const int e0 = blockIdx.y * 64;
  const int tid  = threadIdx.x;
  const int lane = tid & 63, wave = tid >> 6;
  const int wr = wave >> 1, wc = wave & 1;
  const int fr = lane & 15, fq = lane >> 4;

  f32x4 acc[4][2];
  #pragma unroll
  for (int m = 0; m < 4; ++m)
    #pragma unroll
    for (int n = 0; n < 2; ++n) acc[m][n] = (f32x4){0.f, 0.f, 0.f, 0.f};

  const unsigned short* aB = att + (size_t)(b * T_ + i0) * K3;
  const unsigned short* bB = GT + ((size_t)b * NE_ + e0) * K3;

  for (int k0 = 0; k0 < K3; k0 += 32) {
    __syncthreads();
    #pragma unroll
    for (int rdi = 0; rdi < 2; ++rdi) {
      const int q = rdi * 256 + tid;
      const int row = q >> 2, koff = (q & 3) * 8;
      __builtin_amdgcn_global_load_lds(
          (const AS1 void*)(aB + (size_t)row * K3 + k0 + koff),
          (AS3 void*)(As + q * 8), 16, 0, 0);
    }
    {
      const int q = tid;
      const int row = q >> 2, koff = (q & 3) * 8;
      __builtin_amdgcn_global_load_lds(
          (const AS1 void*)(bB + (size_t)row * K3 + k0 + koff),
          (AS3 void*)(Bs + q * 8), 16, 0, 0);
    }
    __syncthreads();
    bf16x8 af[4], bf[2];
    #pragma unroll
    for (int m = 0; m < 4; ++m)
      af[m] = *(const bf16x8*)&As[(wr * 64 + m * 16 + fr) * 32 + fq * 8];
    #pragma unroll
    for (int n = 0; n < 2; ++n)
      bf[n] = *(const bf16x8*)&Bs[(wc * 32 + n * 16 + fr) * 32 + fq * 8];
    #pragma unroll
    for (int m = 0; m < 4; ++m)
      #pragma unroll
      for (int n = 0; n < 2; ++n)
        acc[m][n] = __builtin_amdgcn_mfma_f32_16x16x32_bf16(af[m], bf[n], acc[m][n], 0, 0, 0);
  }

  #pragma unroll
  for (int m = 0; m < 4; ++m)
    #pragma unroll
    for (int n = 0; n < 2; ++n) {
      const int i = i0 + wr * 64 + m * 16 + fq * 4;
      const int e = e0 + wc * 32 + n * 16 + fr;
      const float be = bias[e];
      #pragma unroll
      for (int g = 0; g < 4; ++g)
        y[(size_t)(b * T_ + i + g) * NE_ + e] = acc[m][n][g] + be;
    }
}

// ---------------------------------------------------------------------------
// Kernel 2: att[b][i][j*4+h] = softmax_j(cooc[t_i, t_j, h]) + eye  (bf16)
// ---------------------------------------------------------------------------
__global__ __launch_bounds__(64) void softmax_k(
    const int* __restrict__ x, const float* __restrict__ cooc,
    unsigned short* __restrict__ att) {
  const int bi = blockIdx.x;
  const int b = bi >> 9, i = bi & (T_ - 1);
  const int lane = threadIdx.x;
  const int ti = x[b * T_ + i];
  const float* crow = cooc + (size_t)ti * D_;

  float w[8][4];
  #pragma unroll
  for (int r = 0; r < 8; ++r) {
    const int j = lane + r * 64;
    const int tj = x[b * T_ + j];
    const float4 v = *(const float4*)(crow + (size_t)tj * H_);
    w[r][0] = v.x; w[r][1] = v.y; w[r][2] = v.z; w[r][3] = v.w;
  }
  float m[4] = {-1e30f, -1e30f, -1e30f, -1e30f};
  #pragma unroll
  for (int r = 0; r < 8; ++r)
    #pragma unroll
    for (int h = 0; h < 4; ++h) m[h] = fmaxf(m[h], w[r][h]);
  #pragma unroll
  for (int off = 32; off > 0; off >>= 1)
    #pragma unroll
    for (int h = 0; h < 4; ++h) m[h] = fmaxf(m[h], __shfl_xor(m[h], off));
  float s[4] = {0.f, 0.f, 0.f, 0.f};
  #pragma unroll
  for (int r = 0; r < 8; ++r)
    #pragma unroll
    for (int h = 0; h < 4; ++h) { w[r][h] = __expf(w[r][h] - m[h]); s[h] += w[r][h]; }
  #pragma unroll
  for (int off = 32; off > 0; off >>= 1)
    #pragma unroll
    for (int h = 0; h < 4; ++h) s[h] += __shfl_xor(s[h], off);
  float inv[4];
  #pragma unroll
  for (int h = 0; h < 4; ++h) inv[h] = 1.f / s[h];

  unsigned short* arow = att + (size_t)(b * T_ + i) * (T_ * H_);
  #pragma unroll
  for (int r = 0; r < 8; ++r) {
    const int j = lane + r * 64;
    const float d = (j == i) ? 1.f : 0.f;
    ushort4 o;
    o.x = f2bf(w[r][0] * inv[0] + d);
    o.y = f2bf(w[r][1] * inv[1] + d);
    o.z = f2bf(w[r][2] * inv[2] + d);
    o.w = f2bf(w[r][3] * inv[3] + d);
    *(ushort4*)(arow + (size_t)j * H_) = o;
  }
}

// ---------------------------------------------------------------------------
// Round-1 fallback kernels (tiny ws)
// ---------------------------------------------------------------------------
__global__ __launch_bounds__(256) void gemm1_k(
    const float* __restrict__ pw, const float* __restrict__ cooc,
    unsigned short* __restrict__ mtT) {
  __shared__ unsigned short As[128 * 32];
  __shared__ unsigned short Bs[64 * 32];
  const int h  = blockIdx.z;
  const int e0 = blockIdx.x * 128;
  const int t0 = blockIdx.y * 64;
  const int tid  = threadIdx.x;
  const int lane = tid & 63, wave = tid >> 6;
  const int wr = wave >> 1, wc = wave & 1;
  const int fr = lane & 15, fq = lane >> 4;

  f32x4 acc[4][2];
  #pragma unroll
  for (int m = 0; m < 4; ++m)
    #pragma unroll
    for (int n = 0; n < 2; ++n) acc[m][n] = (f32x4){0.f, 0.f, 0.f, 0.f};

  const float* aB = pw + (size_t)e0 * PWROW + (size_t)h * D_;
  const float* bB = cooc + (size_t)t0 * D_;

  for (int k0 = 0; k0 < D_; k0 += 32) {
    __syncthreads();
    #pragma unroll
    for (int c = 0; c < 4; ++c) {
      const int fe = (c * 256 + tid) * 4;
      const int row = fe >> 5, k = fe & 31;
      const float4 v = *(const float4*)(aB + (size_t)row * PWROW + k0 + k);
      ushort4 o; o.x = f2bf(v.x); o.y = f2bf(v.y); o.z = f2bf(v.z); o.w = f2bf(v.w);
      *(ushort4*)&As[fe] = o;
    }
    #pragma unroll
    for (int c = 0; c < 2; ++c) {
      const int fe = (c * 256 + tid) * 4;
      const int row = fe >> 5, k = fe & 31;
      const float4 v = *(const float4*)(bB + (size_t)row * D_ + k0 + k);
      ushort4 o; o.x = f2bf(v.x); o.y = f2bf(v.y); o.z = f2bf(v.z); o.w = f2bf(v.w);
      *(ushort4*)&Bs[fe] = o;
    }
    __syncthreads();
    bf16x8 af[4], bf[2];
    #pragma unroll
    for (int m = 0; m < 4; ++m)
      af[m] = *(const bf16x8*)&As[(wr * 64 + m * 16 + fr) * 32 + fq * 8];
    #pragma unroll
    for (int n = 0; n < 2; ++n)
      bf[n] = *(const bf16x8*)&Bs[(wc * 32 + n * 16 + fr) * 32 + fq * 8];
    #pragma unroll
    for (int m = 0; m < 4; ++m)
      #pragma unroll
      for (int n = 0; n < 2; ++n)
        acc[m][n] = __builtin_amdgcn_mfma_f32_16x16x32_bf16(af[m], bf[n], acc[m][n], 0, 0, 0);
  }
  #pragma unroll
  for (int m = 0; m < 4; ++m)
    #pragma unroll
    for (int n = 0; n < 2; ++n) {
      const int e = e0 + wr * 64 + m * 16 + fq * 4;
      const int t = t0 + wc * 32 + n * 16 + fr;
      #pragma unroll
      for (int g = 0; g < 4; ++g)
        mtT[(size_t)(e + g) * D_ + t * H_ + h] = f2bf(acc[m][n][g]);
    }
}

__global__ __launch_bounds__(256) void gemm3_k(
    const unsigned short* __restrict__ att, const unsigned short* __restrict__ mtT,
    const int* __restrict__ x, const float* __restrict__ bias,
    float* __restrict__ y) {
  __shared__ unsigned short As[64 * 32];
  __shared__ unsigned short Bs[128 * 32];
  const int b  = blockIdx.z;
  const int i0 = blockIdx.x * 64;
  const int e0 = blockIdx.y * 128;
  const int tid  = threadIdx.x;
  const int lane = tid & 63, wave = tid >> 6;
  const int wr = wave >> 1, wc = wave & 1;
  const int fr = lane & 15, fq = lane >> 4;

  f32x4 acc[2][4];
  #pragma unroll
  for (int m = 0; m < 2; ++m)
    #pragma unroll
    for (int n = 0; n < 4; ++n) acc[m][n] = (f32x4){0.f, 0.f, 0.f, 0.f};

  const unsigned short* aB = att + (size_t)(b * T_ + i0) * (T_ * H_);

  for (int ks = 0; ks < 64; ++ks) {
    const int k0 = ks * 32;
    __syncthreads();
    {
      const int fe = tid * 8;
      const int row = fe >> 5, k = fe & 31;
      const uint4 v = *(const uint4*)(aB + (size_t)row * (T_ * H_) + k0 + k);
      *(uint4*)&As[fe] = v;
    }
    #pragma unroll
    for (int c = 0; c < 4; ++c) {
      const int q = c * 256 + tid;
      const int n = q >> 3, j8 = q & 7;
      const int tj = x[b * T_ + ks * 8 + j8];
      const uint2 v = *(const uint2*)(mtT + (size_t)(e0 + n) * D_ + tj * H_);
      *(uint2*)&Bs[n * 32 + j8 * 4] = v;
    }
    __syncthreads();
    bf16x8 af[2], bf[4];
    #pragma unroll
    for (int m = 0; m < 2; ++m)
      af[m] = *(const bf16x8*)&As[(wr * 32 + m * 16 + fr) * 32 + fq * 8];
    #pragma unroll
    for (int n = 0; n < 4; ++n)
      bf[n] = *(const bf16x8*)&Bs[(wc * 64 + n * 16 + fr) * 32 + fq * 8];
    #pragma unroll
    for (int m = 0; m < 2; ++m)
      #pragma unroll
      for (int n = 0; n < 4; ++n)
        acc[m][n] = __builtin_amdgcn_mfma_f32_16x16x32_bf16(af[m], bf[n], acc[m][n], 0, 0, 0);
  }
  #pragma unroll
  for (int m = 0; m < 2; ++m)
    #pragma unroll
    for (int n = 0; n < 4; ++n) {
      const int i = i0 + wr * 32 + m * 16 + fq * 4;
      const int e = e0 + wc * 64 + n * 16 + fr;
      const float be = bias[e];
      #pragma unroll
      for (int g = 0; g < 4; ++g)
        y[(size_t)(b * T_ + i + g) * NE_ + e] = acc[m][n][g] + be;
    }
}

// ---------------------------------------------------------------------------
extern "C" void kernel_launch(void* const* d_in, const int* in_sizes, int n_in,
                              void* d_out, int out_size, void* d_ws, size_t ws_size,
                              hipStream_t stream) {
  const int*   x    = (const int*)d_in[0];
  const float* cooc = (const float*)d_in[1];
  const float* pw   = (const float*)d_in[2];
  const float* pb   = (const float*)d_in[3];
  float* y = (float*)d_out;

  const size_t BQ_E = (size_t)V_ * D_;           // 16777216

  unsigned short* mtT = (unsigned short*)d_ws;   // == P0
  // ws layout: [P0..P{nz-1}][Bq]. After gemm1: GT aliases Bq (25.2<=33.5MB);
  // after rgather: att aliases P0..P1 (16.8 <= nz*12.6MB, nz>=2).
  auto need = [&](int c) { return ((size_t)c * MTT_E + BQ_E) * 2; };

  int nz = 0;
  if      (ws_size >= need(8)) nz = 8;
  else if (ws_size >= need(4)) nz = 4;
  else if (ws_size >= need(2)) nz = 2;

  if (nz >= 2) {
    unsigned short* Bq  = mtT + (size_t)nz * MTT_E;
    unsigned short* GT  = Bq;   // alias: valid after gemm1pA
    unsigned short* att = mtT;  // alias: valid after rgather
    hipLaunchKernelGGL(cvt_k, dim3(2048), dim3(256), 0, stream,
                       cooc, Bq, (int)(BQ_E / 4));
    hipLaunchKernelGGL(gemm1pA_k, dim3(M1 / 256, V_ / 256, nz), dim3(512), 0,
                       stream, pw, Bq, mtT, D_ / nz);
    hipLaunchKernelGGL(rgather_k, dim3(NE_), dim3(256), 0, stream, mtT, x, GT, nz);
    hipLaunchKernelGGL(softmax_k, dim3(B_ * T_), dim3(64), 0, stream, x, cooc, att);
    hipLaunchKernelGGL(gemm3f_k, dim3(T_ / 128, NE_ / 64, B_), dim3(256), 0, stream,
                       att, GT, pb, y);
  } else {
    // Fallback: round-1 path (29.4 MB ws)
    unsigned short* att = mtT + MTT_E;
    hipLaunchKernelGGL(gemm1_k, dim3(NE_ / 128, V_ / 64, H_), dim3(256), 0, stream,
                       pw, cooc, mtT);
    hipLaunchKernelGGL(softmax_k, dim3(B_ * T_), dim3(64), 0, stream, x, cooc, att);
    hipLaunchKernelGGL(gemm3_k, dim3(T_ / 64, NE_ / 128, B_), dim3(256), 0, stream,
                       att, mtT, x, pb, y);
  }
}

// Round 10
// 232.103 us; speedup vs baseline: 1.9602x; 1.9602x over previous
//
#include <hip/hip_runtime.h>
#include <stdint.h>

// Problem constants
#define B_    8
#define T_    512
#define V_    2048
#define H_    4
#define NE_   768
#define D_    8192      // V_*H_
#define PWROW 32768     // V_*H_*H_
#define M1    3072      // NE_*H_
#define K3    2048      // T_*H_
#define MTT_E 6291456UL // NE_*D_

#define AS1 __attribute__((address_space(1)))
#define AS3 __attribute__((address_space(3)))

typedef __attribute__((ext_vector_type(8))) short bf16x8;
typedef __attribute__((ext_vector_type(4))) float f32x4;

__device__ __forceinline__ unsigned short f2bf(float f) {
  union { float f; unsigned int u; } c; c.f = f;
  unsigned int u = c.u;
  return (unsigned short)((u + 0x7FFFu + ((u >> 16) & 1u)) >> 16);
}
__device__ __forceinline__ float bf2f(unsigned short s) {
  union { unsigned int u; float f; } c; c.u = ((unsigned int)s) << 16;
  return c.f;
}

// ---------------------------------------------------------------------------
// fp32 -> bf16 convert of BOTH inputs in one launch.
// dst layout: [Bq (from cooc)][Aq (from pw)] contiguous.
// ---------------------------------------------------------------------------
__global__ __launch_bounds__(256) void cvtAB_k(
    const float* __restrict__ cooc, const float* __restrict__ pw,
    unsigned short* __restrict__ dst, int bq4, int n4) {
  int i = blockIdx.x * 256 + threadIdx.x;
  const int stride = gridDim.x * 256;
  for (; i < n4; i += stride) {
    const float4 v = (i < bq4) ? ((const float4*)cooc)[i]
                               : ((const float4*)pw)[i - bq4];
    ushort4 o;
    o.x = f2bf(v.x); o.y = f2bf(v.y); o.z = f2bf(v.z); o.w = f2bf(v.w);
    ((ushort4*)dst)[i] = o;
  }
}

// ---------------------------------------------------------------------------
// Kernel 1 (pipelined 256x256, PROVEN round-6/8): C[m][t] over K-slice z.
// 8 waves (2M x 4N), BK=64, 128KB LDS double-buffer, global_load_lds 16B
// staging with counted vmcnt(8) (loads span barriers), chunk-XOR swizzle
// (phys16Bchunk = logical ^ (row&7)) on BOTH stage-source and ds_read
// offsets, setprio around MFMA cluster.
// Register budget note (round-9 lesson): acc=128 AGPR + ~112 VGPR is at the
// 2-waves/SIMD cap; do NOT add reg-staged operands here (spills -> 3.4x).
// Output: partial z in mtT scatter layout [e][t*4+h], bf16, ushort4 stores.
// ---------------------------------------------------------------------------
__global__ __launch_bounds__(512, 2) void gemm1p_k(
    const unsigned short* __restrict__ Aq,   // [3072][8192]
    const unsigned short* __restrict__ Bq,   // [2048][8192]
    unsigned short* __restrict__ P,          // partials, z-strided by MTT_E
    int kk_per) {
  __shared__ unsigned short lds[2][2][256 * 64];   // [dbuf][A=0/B=1] 128 KB
  const int r0 = blockIdx.x * 256;   // m
  const int t0 = blockIdx.y * 256;   // t
  const int z  = blockIdx.z;
  const int kbeg = z * kk_per;
  const int NT = kk_per / 64;
  const int tid  = threadIdx.x;
  const int lane = tid & 63, w = tid >> 6;
  const int wm = w >> 2, wn = w & 3;
  const int fr = lane & 15, fq = lane >> 4;
  unsigned short* __restrict__ Pz = P + (size_t)z * MTT_E;

  f32x4 acc[8][4];
  #pragma unroll
  for (int m = 0; m < 8; ++m)
    #pragma unroll
    for (int n = 0; n < 4; ++n) acc[m][n] = (f32x4){0.f, 0.f, 0.f, 0.f};

  // Stage one 256x64 A-tile + B-tile into dbuf d, global K-offset k0.
  // Physical chunk q holds logical col16 c = (q&7) ^ (row&7), row = q>>3.
  auto STAGE = [&](int d, int k0) {
    #pragma unroll
    for (int i = 0; i < 4; ++i) {
      const int q   = (w * 4 + i) * 64 + lane;
      const int row = q >> 3;
      const int c16 = (q & 7) ^ (row & 7);
      __builtin_amdgcn_global_load_lds(
          (const AS1 void*)(Aq + (size_t)(r0 + row) * D_ + k0 + c16 * 8),
          (AS3 void*)(&lds[d][0][(w * 4 + i) * 512]), 16, 0, 0);
    }
    #pragma unroll
    for (int i = 0; i < 4; ++i) {
      const int q   = (w * 4 + i) * 64 + lane;
      const int row = q >> 3;
      const int c16 = (q & 7) ^ (row & 7);
      __builtin_amdgcn_global_load_lds(
          (const AS1 void*)(Bq + (size_t)(t0 + row) * D_ + k0 + c16 * 8),
          (AS3 void*)(&lds[d][1][(w * 4 + i) * 512]), 16, 0, 0);
    }
  };
  // swizzled ushort offset of logical (row, col16)
  #define OFFS(r, c) ((r) * 64 + (((c) ^ ((r) & 7)) * 8))

  STAGE(0, kbeg);

  for (int kt = 0; kt < NT; ++kt) {
    if (kt + 1 < NT) {
      STAGE((kt + 1) & 1, kbeg + (kt + 1) * 64);
      asm volatile("s_waitcnt vmcnt(8)" ::: "memory");   // stage(kt) landed
    } else {
      asm volatile("s_waitcnt vmcnt(0)" ::: "memory");
    }
    __builtin_amdgcn_s_barrier();
    __builtin_amdgcn_sched_barrier(0);

    const unsigned short* Ab = &lds[kt & 1][0][0];
    const unsigned short* Bb = &lds[kt & 1][1][0];

    bf16x8 afA[4][2], afB[4][2], bf0[2][2], bf1[2][2];
    #pragma unroll
    for (int m = 0; m < 4; ++m)
      #pragma unroll
      for (int kk = 0; kk < 2; ++kk)
        afA[m][kk] = *(const bf16x8*)&Ab[OFFS(wm * 128 + m * 16 + fr, kk * 4 + fq)];
    #pragma unroll
    for (int n = 0; n < 2; ++n)
      #pragma unroll
      for (int kk = 0; kk < 2; ++kk) {
        bf0[n][kk] = *(const bf16x8*)&Bb[OFFS(wn * 64 + n * 16 + fr, kk * 4 + fq)];
        bf1[n][kk] = *(const bf16x8*)&Bb[OFFS(wn * 64 + 32 + n * 16 + fr, kk * 4 + fq)];
      }

    __builtin_amdgcn_s_setprio(1);
    #pragma unroll
    for (int m = 0; m < 4; ++m)
      #pragma unroll
      for (int n = 0; n < 2; ++n)
        #pragma unroll
        for (int kk = 0; kk < 2; ++kk) {
          acc[m][n]     = __builtin_amdgcn_mfma_f32_16x16x32_bf16(afA[m][kk], bf0[n][kk], acc[m][n], 0, 0, 0);
          acc[m][n + 2] = __builtin_amdgcn_mfma_f32_16x16x32_bf16(afA[m][kk], bf1[n][kk], acc[m][n + 2], 0, 0, 0);
        }
    #pragma unroll
    for (int m = 0; m < 4; ++m)
      #pragma unroll
      for (int kk = 0; kk < 2; ++kk)
        afB[m][kk] = *(const bf16x8*)&Ab[OFFS(wm * 128 + 64 + m * 16 + fr, kk * 4 + fq)];
    #pragma unroll
    for (int m = 0; m < 4; ++m)
      #pragma unroll
      for (int n = 0; n < 2; ++n)
        #pragma unroll
        for (int kk = 0; kk < 2; ++kk) {
          acc[m + 4][n]     = __builtin_amdgcn_mfma_f32_16x16x32_bf16(afB[m][kk], bf0[n][kk], acc[m + 4][n], 0, 0, 0);
          acc[m + 4][n + 2] = __builtin_amdgcn_mfma_f32_16x16x32_bf16(afB[m][kk], bf1[n][kk], acc[m + 4][n + 2], 0, 0, 0);
        }
    __builtin_amdgcn_s_setprio(0);

    __builtin_amdgcn_s_barrier();      // readers done before next stage rewrites
    __builtin_amdgcn_sched_barrier(0);
  }
  #undef OFFS

  // Epilogue: rows rbase..rbase+3 (rbase%4==0) -> one ushort4 at
  // Pz[(rbase>>2)*D_ + t*4].
  #pragma unroll
  for (int m = 0; m < 8; ++m)
    #pragma unroll
    for (int n = 0; n < 4; ++n) {
      const int rbase = r0 + wm * 128 + m * 16 + fq * 4;
      const int t = t0 + wn * 64 + n * 16 + fr;
      ushort4 o;
      o.x = f2bf(acc[m][n][0]); o.y = f2bf(acc[m][n][1]);
      o.z = f2bf(acc[m][n][2]); o.w = f2bf(acc[m][n][3]);
      *(ushort4*)&Pz[(size_t)(rbase >> 2) * D_ + t * H_] = o;
    }
}

// ---------------------------------------------------------------------------
// Kernel 1 (m97 structure, proven): used when ws only fits nz<=2.
// ---------------------------------------------------------------------------
__global__ __launch_bounds__(256) void gemm1f_k(
    const unsigned short* __restrict__ Aq,
    const unsigned short* __restrict__ Bq,
    unsigned short* __restrict__ P, int kk) {
  __shared__ unsigned short As[128 * 32];
  __shared__ unsigned short Bs[128 * 32];
  const int r0 = blockIdx.x * 128;
  const int t0 = blockIdx.y * 128;
  const int z  = blockIdx.z;
  const int kbeg = z * kk, kend = kbeg + kk;
  const int tid  = threadIdx.x;
  const int lane = tid & 63, wave = tid >> 6;
  const int wr = wave >> 1, wc = wave & 1;
  const int fr = lane & 15, fq = lane >> 4;
  const int l4 = lane >> 2, lb = lane & 3;
  unsigned short* __restrict__ Pz = P + (size_t)z * MTT_E;

  f32x4 acc[4][4];
  #pragma unroll
  for (int m = 0; m < 4; ++m)
    #pragma unroll
    for (int n = 0; n < 4; ++n) acc[m][n] = (f32x4){0.f, 0.f, 0.f, 0.f};

  for (int k0 = kbeg; k0 < kend; k0 += 32) {
    __syncthreads();
    #pragma unroll
    for (int c = 0; c < 2; ++c) {
      const int ch  = wave * 2 + c;
      const int row = ch * 16 + l4;
      __builtin_amdgcn_global_load_lds(
          (const AS1 void*)(Aq + (size_t)(r0 + row) * D_ + k0 + lb * 8),
          (AS3 void*)(As + ch * 512), 16, 0, 0);
      __builtin_amdgcn_global_load_lds(
          (const AS1 void*)(Bq + (size_t)(t0 + row) * D_ + k0 + lb * 8),
          (AS3 void*)(Bs + ch * 512), 16, 0, 0);
    }
    __syncthreads();
    bf16x8 af[4], bf[4];
    #pragma unroll
    for (int m = 0; m < 4; ++m)
      af[m] = *(const bf16x8*)&As[(wr * 64 + m * 16 + fr) * 32 + fq * 8];
    #pragma unroll
    for (int n = 0; n < 4; ++n)
      bf[n] = *(const bf16x8*)&Bs[(wc * 64 + n * 16 + fr) * 32 + fq * 8];
    #pragma unroll
    for (int m = 0; m < 4; ++m)
      #pragma unroll
      for (int n = 0; n < 4; ++n)
        acc[m][n] = __builtin_amdgcn_mfma_f32_16x16x32_bf16(af[m], bf[n], acc[m][n], 0, 0, 0);
  }
  #pragma unroll
  for (int m = 0; m < 4; ++m)
    #pragma unroll
    for (int n = 0; n < 4; ++n) {
      const int rbase = r0 + wr * 64 + m * 16 + fq * 4;
      const int t = t0 + wc * 64 + n * 16 + fr;
      ushort4 o;
      o.x = f2bf(acc[m][n][0]); o.y = f2bf(acc[m][n][1]);
      o.z = f2bf(acc[m][n][2]); o.w = f2bf(acc[m][n][3]);
      *(ushort4*)&Pz[(size_t)(rbase >> 2) * D_ + t * H_] = o;
    }
}

// ---------------------------------------------------------------------------
// Fat kernel: fused {reduce+gather} (blocks 0..NE_-1) + {softmax} (blocks
// NE_..NE_+1023). The two halves are independent (P->GT vs cooc->att) and
// complementary (BW-bound streaming vs latency-bound random reads), so they
// co-schedule across CUs; saves one launch and hides softmax under rgather.
//
// rgather half (proven round-8): per e-row block, stream-sum nz partials
// coalesced into a 16KB LDS row (fp32 sum, bf16 round), then gather 8B
// chunks into GT[b][e][j*4+h].
// softmax half (proven round-1): 4 (b,i) rows per block, one per wave;
// att[b][i][j*4+h] = softmax_j(cooc[t_i,t_j,h]) + eye, bf16.
// ---------------------------------------------------------------------------
__global__ __launch_bounds__(256) void rgsm_k(
    const unsigned short* __restrict__ P, const int* __restrict__ x,
    unsigned short* __restrict__ GT, int nz,
    const float* __restrict__ cooc, unsigned short* __restrict__ att) {
  const int tid = threadIdx.x;
  const int lane = tid & 63, wave = tid >> 6;

  if (blockIdx.x < NE_) {
    // ---------------- reduce + gather ----------------
    __shared__ int toks[B_ * T_];          // 16 KB
    __shared__ unsigned short row[D_];     // 16 KB
    #pragma unroll
    for (int c = 0; c < 16; ++c) toks[c * 256 + tid] = x[c * 256 + tid];

    const int e = blockIdx.x;
    const unsigned short* prow = P + (size_t)e * D_;

    float s[8][4];
    #pragma unroll
    for (int i = 0; i < 8; ++i) { s[i][0] = s[i][1] = s[i][2] = s[i][3] = 0.f; }
    for (int z = 0; z < nz; ++z) {
      const unsigned short* pz = prow + (size_t)z * MTT_E;
      #pragma unroll
      for (int i = 0; i < 8; ++i) {
        const ushort4 v = *(const ushort4*)(pz + (size_t)(i * 256 + tid) * 4);
        s[i][0] += bf2f(v.x); s[i][1] += bf2f(v.y);
        s[i][2] += bf2f(v.z); s[i][3] += bf2f(v.w);
      }
    }
    #pragma unroll
    for (int i = 0; i < 8; ++i) {
      ushort4 o;
      o.x = f2bf(s[i][0]); o.y = f2bf(s[i][1]);
      o.z = f2bf(s[i][2]); o.w = f2bf(s[i][3]);
      *(ushort4*)&row[(i * 256 + tid) * 4] = o;
    }
    __syncthreads();

    #pragma unroll
    for (int bb = 0; bb < 2; ++bb) {
      const int b = wave * 2 + bb;
      unsigned short* grow = GT + ((size_t)b * NE_ + e) * K3;
      const int* tb = toks + b * T_;
      #pragma unroll
      for (int r = 0; r < 8; ++r) {
        const int j = r * 64 + lane;
        const uint2 v = *(const uint2*)&row[tb[j] * H_];
        *(uint2*)(grow + j * H_) = v;
      }
    }
  } else {
    // ---------------- softmax (+eye) ----------------
    const int bi = (blockIdx.x - NE_) * 4 + wave;   // 0..4095
    const int b = bi >> 9, i = bi & (T_ - 1);
    const int ti = x[b * T_ + i];
    const float* crow = cooc + (size_t)ti * D_;

    float wv[8][4];
    #pragma unroll
    for (int r = 0; r < 8; ++r) {
      const int j = lane + r * 64;
      const int tj = x[b * T_ + j];
      const float4 v = *(const float4*)(crow + (size_t)tj * H_);
      wv[r][0] = v.x; wv[r][1] = v.y; wv[r][2] = v.z; wv[r][3] = v.w;
    }
    float m[4] = {-1e30f, -1e30f, -1e30f, -1e30f};
    #pragma unroll
    for (int r = 0; r < 8; ++r)
      #pragma unroll
      for (int h = 0; h < 4; ++h) m[h] = fmaxf(m[h], wv[r][h]);
    #pragma unroll
    for (int off = 32; off > 0; off >>= 1)
      #pragma unroll
      for (int h = 0; h < 4; ++h) m[h] = fmaxf(m[h], __shfl_xor(m[h], off));
    float sm[4] = {0.f, 0.f, 0.f, 0.f};
    #pragma unroll
    for (int r = 0; r < 8; ++r)
      #pragma unroll
      for (int h = 0; h < 4; ++h) { wv[r][h] = __expf(wv[r][h] - m[h]); sm[h] += wv[r][h]; }
    #pragma unroll
    for (int off = 32; off > 0; off >>= 1)
      #pragma unroll
      for (int h = 0; h < 4; ++h) sm[h] += __shfl_xor(sm[h], off);
    float inv[4];
    #pragma unroll
    for (int h = 0; h < 4; ++h) inv[h] = 1.f / sm[h];

    unsigned short* arow = att + (size_t)(b * T_ + i) * K3;
    #pragma unroll
    for (int r = 0; r < 8; ++r) {
      const int j = lane + r * 64;
      const float d = (j == i) ? 1.f : 0.f;
      ushort4 o;
      o.x = f2bf(wv[r][0] * inv[0] + d);
      o.y = f2bf(wv[r][1] * inv[1] + d);
      o.z = f2bf(wv[r][2] * inv[2] + d);
      o.w = f2bf(wv[r][3] * inv[3] + d);
      *(ushort4*)(arow + (size_t)j * H_) = o;
    }
  }
}

// ---------------------------------------------------------------------------
// Kernel 3 (dense): y[b][i][e] = sum_k att[b,i,k] * GT[b,e,k] + pb[e]
// ---------------------------------------------------------------------------
__global__ __launch_bounds__(256) void gemm3f_k(
    const unsigned short* __restrict__ att,
    const unsigned short* __restrict__ GT,
    const float* __restrict__ bias,
    float* __restrict__ y) {
  __shared__ unsigned short As[128 * 32];
  __shared__ unsigned short Bs[64 * 32];
  const int b  = blockIdx.z;
  const int i0 = blockIdx.x * 128;
  const int e0 = blockIdx.y * 64;
  const int tid  = threadIdx.x;
  const int lane = tid & 63, wave = tid >> 6;
  const int wr = wave >> 1, wc = wave & 1;
  const int fr = lane & 15, fq = lane >> 4;

  f32x4 acc[4][2];
  #pragma unroll
  for (int m = 0; m < 4; ++m)
    #pragma unroll
    for (int n = 0; n < 2; ++n) acc[m][n] = (f32x4){0.f, 0.f, 0.f, 0.f};

  const unsigned short* aB = att + (size_t)(b * T_ + i0) * K3;
  const unsigned short* bB = GT + ((size_t)b * NE_ + e0) * K3;

  for (int k0 = 0; k0 < K3; k0 += 32) {
    __syncthreads();
    #pragma unroll
    for (int rdi = 0; rdi < 2; ++rdi) {
      const int q = rdi * 256 + tid;
      const int row = q >> 2, koff = (q & 3) * 8;
      __builtin_amdgcn_global_load_lds(
          (const AS1 void*)(aB + (size_t)row * K3 + k0 + koff),
          (AS3 void*)(As + q * 8), 16, 0, 0);
    }
    {
      const int q = tid;
      const int row = q >> 2, koff = (q & 3) * 8;
      __builtin_amdgcn_global_load_lds(
          (const AS1 void*)(bB + (size_t)row * K3 + k0 + koff),
          (AS3 void*)(Bs + q * 8), 16, 0, 0);
    }
    __syncthreads();
    bf16x8 af[4], bf[2];
    #pragma unroll
    for (int m = 0; m < 4; ++m)
      af[m] = *(const bf16x8*)&As[(wr * 64 + m * 16 + fr) * 32 + fq * 8];
    #pragma unroll
    for (int n = 0; n < 2; ++n)
      bf[n] = *(const bf16x8*)&Bs[(wc * 32 + n * 16 + fr) * 32 + fq * 8];
    #pragma unroll
    for (int m = 0; m < 4; ++m)
      #pragma unroll
      for (int n = 0; n < 2; ++n)
        acc[m][n] = __builtin_amdgcn_mfma_f32_16x16x32_bf16(af[m], bf[n], acc[m][n], 0, 0, 0);
  }

  #pragma unroll
  for (int m = 0; m < 4; ++m)
    #pragma unroll
    for (int n = 0; n < 2; ++n) {
      const int i = i0 + wr * 64 + m * 16 + fq * 4;
      const int e = e0 + wc * 32 + n * 16 + fr;
      const float be = bias[e];
      #pragma unroll
      for (int g = 0; g < 4; ++g)
        y[(size_t)(b * T_ + i + g) * NE_ + e] = acc[m][n][g] + be;
    }
}

// ---------------------------------------------------------------------------
// Kernel 2 (standalone, fallback path only)
// ---------------------------------------------------------------------------
__global__ __launch_bounds__(64) void softmax_k(
    const int* __restrict__ x, const float* __restrict__ cooc,
    unsigned short* __restrict__ att) {
  const int bi = blockIdx.x;
  const int b = bi >> 9, i = bi & (T_ - 1);
  const int lane = threadIdx.x;
  const int ti = x[b * T_ + i];
  const float* crow = cooc + (size_t)ti * D_;

  float w[8][4];
  #pragma unroll
  for (int r = 0; r < 8; ++r) {
    const int j = lane + r * 64;
    const int tj = x[b * T_ + j];
    const float4 v = *(const float4*)(crow + (size_t)tj * H_);
    w[r][0] = v.x; w[r][1] = v.y; w[r][2] = v.z; w[r][3] = v.w;
  }
  float m[4] = {-1e30f, -1e30f, -1e30f, -1e30f};
  #pragma unroll
  for (int r = 0; r < 8; ++r)
    #pragma unroll
    for (int h = 0; h < 4; ++h) m[h] = fmaxf(m[h], w[r][h]);
  #pragma unroll
  for (int off = 32; off > 0; off >>= 1)
    #pragma unroll
    for (int h = 0; h < 4; ++h) m[h] = fmaxf(m[h], __shfl_xor(m[h], off));
  float s[4] = {0.f, 0.f, 0.f, 0.f};
  #pragma unroll
  for (int r = 0; r < 8; ++r)
    #pragma unroll
    for (int h = 0; h < 4; ++h) { w[r][h] = __expf(w[r][h] - m[h]); s[h] += w[r][h]; }
  #pragma unroll
  for (int off = 32; off > 0; off >>= 1)
    #pragma unroll
    for (int h = 0; h < 4; ++h) s[h] += __shfl_xor(s[h], off);
  float inv[4];
  #pragma unroll
  for (int h = 0; h < 4; ++h) inv[h] = 1.f / s[h];

  unsigned short* arow = att + (size_t)(b * T_ + i) * (T_ * H_);
  #pragma unroll
  for (int r = 0; r < 8; ++r) {
    const int j = lane + r * 64;
    const float d = (j == i) ? 1.f : 0.f;
    ushort4 o;
    o.x = f2bf(w[r][0] * inv[0] + d);
    o.y = f2bf(w[r][1] * inv[1] + d);
    o.z = f2bf(w[r][2] * inv[2] + d);
    o.w = f2bf(w[r][3] * inv[3] + d);
    *(ushort4*)(arow + (size_t)j * H_) = o;
  }
}

// ---------------------------------------------------------------------------
// Round-1 fallback kernels (tiny ws)
// ---------------------------------------------------------------------------
__global__ __launch_bounds__(256) void gemm1_k(
    const float* __restrict__ pw, const float* __restrict__ cooc,
    unsigned short* __restrict__ mtT) {
  __shared__ unsigned short As[128 * 32];
  __shared__ unsigned short Bs[64 * 32];
  const int h  = blockIdx.z;
  const int e0 = blockIdx.x * 128;
  const int t0 = blockIdx.y * 64;
  const int tid  = threadIdx.x;
  const int lane = tid & 63, wave = tid >> 6;
  const int wr = wave >> 1, wc = wave & 1;
  const int fr = lane & 15, fq = lane >> 4;

  f32x4 acc[4][2];
  #pragma unroll
  for (int m = 0; m < 4; ++m)
    #pragma unroll
    for (int n = 0; n < 2; ++n) acc[m][n] = (f32x4){0.f, 0.f, 0.f, 0.f};

  const float* aB = pw + (size_t)e0 * PWROW + (size_t)h * D_;
  const float* bB = cooc + (size_t)t0 * D_;

  for (int k0 = 0; k0 < D_; k0 += 32) {
    __syncthreads();
    #pragma unroll
    for (int c = 0; c < 4; ++c) {
      const int fe = (c * 256 + tid) * 4;
      const int row = fe >> 5, k = fe & 31;
      const float4 v = *(const float4*)(aB + (size_t)row * PWROW + k0 + k);
      ushort4 o; o.x = f2bf(v.x); o.y = f2bf(v.y); o.z = f2bf(v.z); o.w = f2bf(v.w);
      *(ushort4*)&As[fe] = o;
    }
    #pragma unroll
    for (int c = 0; c < 2; ++c) {
      const int fe = (c * 256 + tid) * 4;
      const int row = fe >> 5, k = fe & 31;
      const float4 v = *(const float4*)(bB + (size_t)row * D_ + k0 + k);
      ushort4 o; o.x = f2bf(v.x); o.y = f2bf(v.y); o.z = f2bf(v.z); o.w = f2bf(v.w);
      *(ushort4*)&Bs[fe] = o;
    }
    __syncthreads();
    bf16x8 af[4], bf[2];
    #pragma unroll
    for (int m = 0; m < 4; ++m)
      af[m] = *(const bf16x8*)&As[(wr * 64 + m * 16 + fr) * 32 + fq * 8];
    #pragma unroll
    for (int n = 0; n < 2; ++n)
      bf[n] = *(const bf16x8*)&Bs[(wc * 32 + n * 16 + fr) * 32 + fq * 8];
    #pragma unroll
    for (int m = 0; m < 4; ++m)
      #pragma unroll
      for (int n = 0; n < 2; ++n)
        acc[m][n] = __builtin_amdgcn_mfma_f32_16x16x32_bf16(af[m], bf[n], acc[m][n], 0, 0, 0);
  }
  #pragma unroll
  for (int m = 0; m < 4; ++m)
    #pragma unroll
    for (int n = 0; n < 2; ++n) {
      const int e = e0 + wr * 64 + m * 16 + fq * 4;
      const int t = t0 + wc * 32 + n * 16 + fr;
      #pragma unroll
      for (int g = 0; g < 4; ++g)
        mtT[(size_t)(e + g) * D_ + t * H_ + h] = f2bf(acc[m][n][g]);
    }
}

__global__ __launch_bounds__(256) void gemm3_k(
    const unsigned short* __restrict__ att, const unsigned short* __restrict__ mtT,
    const int* __restrict__ x, const float* __restrict__ bias,
    float* __restrict__ y) {
  __shared__ unsigned short As[64 * 32];
  __shared__ unsigned short Bs[128 * 32];
  const int b  = blockIdx.z;
  const int i0 = blockIdx.x * 64;
  const int e0 = blockIdx.y * 128;
  const int tid  = threadIdx.x;
  const int lane = tid & 63, wave = tid >> 6;
  const int wr = wave >> 1, wc = wave & 1;
  const int fr = lane & 15, fq = lane >> 4;

  f32x4 acc[2][4];
  #pragma unroll
  for (int m = 0; m < 2; ++m)
    #pragma unroll
    for (int n = 0; n < 4; ++n) acc[m][n] = (f32x4){0.f, 0.f, 0.f, 0.f};

  const unsigned short* aB = att + (size_t)(b * T_ + i0) * (T_ * H_);

  for (int ks = 0; ks < 64; ++ks) {
    const int k0 = ks * 32;
    __syncthreads();
    {
      const int fe = tid * 8;
      const int row = fe >> 5, k = fe & 31;
      const uint4 v = *(const uint4*)(aB + (size_t)row * (T_ * H_) + k0 + k);
      *(uint4*)&As[fe] = v;
    }
    #pragma unroll
    for (int c = 0; c < 4; ++c) {
      const int q = c * 256 + tid;
      const int n = q >> 3, j8 = q & 7;
      const int tj = x[b * T_ + ks * 8 + j8];
      const uint2 v = *(const uint2*)(mtT + (size_t)(e0 + n) * D_ + tj * H_);
      *(uint2*)&Bs[n * 32 + j8 * 4] = v;
    }
    __syncthreads();
    bf16x8 af[2], bf[4];
    #pragma unroll
    for (int m = 0; m < 2; ++m)
      af[m] = *(const bf16x8*)&As[(wr * 32 + m * 16 + fr) * 32 + fq * 8];
    #pragma unroll
    for (int n = 0; n < 4; ++n)
      bf[n] = *(const bf16x8*)&Bs[(wc * 64 + n * 16 + fr) * 32 + fq * 8];
    #pragma unroll
    for (int m = 0; m < 2; ++m)
      #pragma unroll
      for (int n = 0; n < 4; ++n)
        acc[m][n] = __builtin_amdgcn_mfma_f32_16x16x32_bf16(af[m], bf[n], acc[m][n], 0, 0, 0);
  }
  #pragma unroll
  for (int m = 0; m < 2; ++m)
    #pragma unroll
    for (int n = 0; n < 4; ++n) {
      const int i = i0 + wr * 32 + m * 16 + fq * 4;
      const int e = e0 + wc * 64 + n * 16 + fr;
      const float be = bias[e];
      #pragma unroll
      for (int g = 0; g < 4; ++g)
        y[(size_t)(b * T_ + i + g) * NE_ + e] = acc[m][n][g] + be;
    }
}

// ---------------------------------------------------------------------------
extern "C" void kernel_launch(void* const* d_in, const int* in_sizes, int n_in,
                              void* d_out, int out_size, void* d_ws, size_t ws_size,
                              hipStream_t stream) {
  const int*   x    = (const int*)d_in[0];
  const float* cooc = (const float*)d_in[1];
  const float* pw   = (const float*)d_in[2];
  const float* pb   = (const float*)d_in[3];
  float* y = (float*)d_out;

  const size_t BQ_E = (size_t)V_ * D_;           // 16777216
  const size_t AQ_E = (size_t)M1 * D_;           // 25165824

  unsigned short* mtT = (unsigned short*)d_ws;   // == P0
  auto need = [&](int c) { return ((size_t)c * MTT_E + BQ_E + AQ_E) * 2; };

  int nz = 0, pipe = 0;
  if      (ws_size >= need(8)) { nz = 8; pipe = 1; }
  else if (ws_size >= need(4)) { nz = 4; pipe = 1; }
  else if (ws_size >= need(2)) { nz = 2; pipe = 0; }
  else if (ws_size >= need(1)) { nz = 1; pipe = 0; }

  if (nz >= 1) {
    unsigned short* Bq  = mtT + (size_t)nz * MTT_E;
    unsigned short* Aq  = Bq + BQ_E;
    unsigned short* GT  = Bq;   // alias: valid after gemm1
    unsigned short* att = Aq;   // alias: valid after gemm1
    hipLaunchKernelGGL(cvtAB_k, dim3(2048), dim3(256), 0, stream,
                       cooc, pw, Bq, (int)(BQ_E / 4), (int)((BQ_E + AQ_E) / 4));
    if (pipe)
      hipLaunchKernelGGL(gemm1p_k, dim3(M1 / 256, V_ / 256, nz), dim3(512), 0,
                         stream, Aq, Bq, mtT, D_ / nz);
    else
      hipLaunchKernelGGL(gemm1f_k, dim3(M1 / 128, V_ / 128, nz), dim3(256), 0,
                         stream, Aq, Bq, mtT, D_ / nz);
    // Fused reduce+gather (blocks 0..767) + softmax (blocks 768..1791)
    hipLaunchKernelGGL(rgsm_k, dim3(NE_ + (B_ * T_) / 4), dim3(256), 0, stream,
                       mtT, x, GT, nz, cooc, att);
    hipLaunchKernelGGL(gemm3f_k, dim3(T_ / 128, NE_ / 64, B_), dim3(256), 0, stream,
                       att, GT, pb, y);
  } else {
    unsigned short* att = mtT + MTT_E;
    hipLaunchKernelGGL(gemm1_k, dim3(NE_ / 128, V_ / 64, H_), dim3(256), 0, stream,
                       pw, cooc, mtT);
    hipLaunchKernelGGL(softmax_k, dim3(B_ * T_), dim3(64), 0, stream, x, cooc, att);
    hipLaunchKernelGGL(gemm3_k, dim3(T_ / 64, NE_ / 128, B_), dim3(256), 0, stream,
                       att, mtT, x, pb, y);
  }
}

// Round 11
// 229.578 us; speedup vs baseline: 1.9818x; 1.0110x over previous
//
#include <hip/hip_runtime.h>
#include <stdint.h>

// Problem constants
#define B_    8
#define T_    512
#define V_    2048
#define H_    4
#define NE_   768
#define D_    8192      // V_*H_
#define PWROW 32768     // V_*H_*H_
#define M1    3072      // NE_*H_
#define K3    2048      // T_*H_
#define MTT_E 6291456UL // NE_*D_

#define AS1 __attribute__((address_space(1)))
#define AS3 __attribute__((address_space(3)))

typedef __attribute__((ext_vector_type(8))) short bf16x8;
typedef __attribute__((ext_vector_type(4))) float f32x4;

__device__ __forceinline__ unsigned short f2bf(float f) {
  union { float f; unsigned int u; } c; c.f = f;
  unsigned int u = c.u;
  return (unsigned short)((u + 0x7FFFu + ((u >> 16) & 1u)) >> 16);
}
__device__ __forceinline__ float bf2f(unsigned short s) {
  union { unsigned int u; float f; } c; c.u = ((unsigned int)s) << 16;
  return c.f;
}

// ---------------------------------------------------------------------------
// fp32 -> bf16 convert of BOTH inputs in one launch.
// dst layout: [Bq (from cooc)][Aq (from pw)] contiguous.
// ---------------------------------------------------------------------------
__global__ __launch_bounds__(256) void cvtAB_k(
    const float* __restrict__ cooc, const float* __restrict__ pw,
    unsigned short* __restrict__ dst, int bq4, int n4) {
  int i = blockIdx.x * 256 + threadIdx.x;
  const int stride = gridDim.x * 256;
  for (; i < n4; i += stride) {
    const float4 v = (i < bq4) ? ((const float4*)cooc)[i]
                               : ((const float4*)pw)[i - bq4];
    ushort4 o;
    o.x = f2bf(v.x); o.y = f2bf(v.y); o.z = f2bf(v.z); o.w = f2bf(v.w);
    ((ushort4*)dst)[i] = o;
  }
}

// ---------------------------------------------------------------------------
// Kernel 1 (128x128, BK=32, pipelined, 3-4 blocks/CU): C[m][t] over K-slice z.
// Rationale (round-10 lesson): the 256^2 version is capped at 1 block/CU by
// LDS(128K) AND regs(~240) -> barriers have no co-resident filler. This tile
// keeps the SAME proven mechanism (global_load_lds 16B, double-buffer,
// counted vmcnt(4) so next tile's loads span the barrier, raw s_barrier,
// setprio, chunk-XOR swizzle) at 32KB LDS / ~120 regs -> 12-16 waves/CU.
// Swizzle (BK=32: 4 chunks/row): phys chunk col pc = c ^ ((row>>1)&3);
// read offset OFFS32 matches (involution both sides).
// Output: partial z in mtT scatter layout [e][t*4+h], bf16 ushort4 stores.
// ---------------------------------------------------------------------------
__global__ __launch_bounds__(256, 4) void gemm1r_k(
    const unsigned short* __restrict__ Aq,   // [3072][8192]
    const unsigned short* __restrict__ Bq,   // [2048][8192]
    unsigned short* __restrict__ P,          // partials, z-strided by MTT_E
    int kk_per) {
  __shared__ unsigned short lds[2][2][128 * 32];   // [dbuf][A=0/B=1], 32 KB
  const int r0 = blockIdx.x * 128;   // m
  const int t0 = blockIdx.y * 128;   // t
  const int z  = blockIdx.z;
  const int kbeg = z * kk_per;
  const int NT = kk_per / 32;
  const int tid  = threadIdx.x;
  const int lane = tid & 63, w = tid >> 6;
  const int wr = w >> 1, wc = w & 1;
  const int fr = lane & 15, fq = lane >> 4;
  unsigned short* __restrict__ Pz = P + (size_t)z * MTT_E;

  f32x4 acc[4][4];
  #pragma unroll
  for (int m = 0; m < 4; ++m)
    #pragma unroll
    for (int n = 0; n < 4; ++n) acc[m][n] = (f32x4){0.f, 0.f, 0.f, 0.f};

  // Stage one 128x32 A-tile + B-tile into dbuf d at K-offset k0.
  // chunk q in [0,512): row = q>>2, c = q&3, source col pc = c ^ ((row>>1)&3).
  // 4 loads/thread total (2 per operand).
  auto STAGE = [&](int d, int k0) {
    #pragma unroll
    for (int op = 0; op < 2; ++op) {
      const unsigned short* G = op ? Bq : Aq;
      const int b0 = op ? t0 : r0;
      #pragma unroll
      for (int i = 0; i < 2; ++i) {
        const int q   = i * 256 + tid;
        const int row = q >> 2;
        const int pc  = (q & 3) ^ ((row >> 1) & 3);
        __builtin_amdgcn_global_load_lds(
            (const AS1 void*)(G + (size_t)(b0 + row) * D_ + k0 + pc * 8),
            (AS3 void*)(&lds[d][op][(i * 256 + w * 64) * 8]), 16, 0, 0);
      }
    }
  };
  // swizzled ushort offset of logical (row, col16) , col16 in [0,4)
  #define OFFS32(r, c) ((r) * 32 + ((((c) ^ (((r) >> 1) & 3))) * 8))

  STAGE(0, kbeg);

  for (int kt = 0; kt < NT; ++kt) {
    if (kt + 1 < NT) {
      STAGE((kt + 1) & 1, kbeg + (kt + 1) * 32);
      asm volatile("s_waitcnt vmcnt(4)" ::: "memory");  // tile kt landed; kt+1 in flight
    } else {
      asm volatile("s_waitcnt vmcnt(0)" ::: "memory");
    }
    __builtin_amdgcn_s_barrier();
    __builtin_amdgcn_sched_barrier(0);

    const unsigned short* Ab = &lds[kt & 1][0][0];
    const unsigned short* Bb = &lds[kt & 1][1][0];
    bf16x8 af[4], bf[4];
    #pragma unroll
    for (int m = 0; m < 4; ++m)
      af[m] = *(const bf16x8*)&Ab[OFFS32(wr * 64 + m * 16 + fr, fq)];
    #pragma unroll
    for (int n = 0; n < 4; ++n)
      bf[n] = *(const bf16x8*)&Bb[OFFS32(wc * 64 + n * 16 + fr, fq)];

    __builtin_amdgcn_s_setprio(1);
    #pragma unroll
    for (int m = 0; m < 4; ++m)
      #pragma unroll
      for (int n = 0; n < 4; ++n)
        acc[m][n] = __builtin_amdgcn_mfma_f32_16x16x32_bf16(af[m], bf[n], acc[m][n], 0, 0, 0);
    __builtin_amdgcn_s_setprio(0);

    __builtin_amdgcn_s_barrier();      // readers done before next STAGE rewrites
    __builtin_amdgcn_sched_barrier(0);
  }
  #undef OFFS32

  // Epilogue: rows rbase..rbase+3 (rbase%4==0) -> one ushort4 at
  // Pz[(rbase>>2)*D_ + t*4].
  #pragma unroll
  for (int m = 0; m < 4; ++m)
    #pragma unroll
    for (int n = 0; n < 4; ++n) {
      const int rbase = r0 + wr * 64 + m * 16 + fq * 4;
      const int t = t0 + wc * 64 + n * 16 + fr;
      ushort4 o;
      o.x = f2bf(acc[m][n][0]); o.y = f2bf(acc[m][n][1]);
      o.z = f2bf(acc[m][n][2]); o.w = f2bf(acc[m][n][3]);
      *(ushort4*)&Pz[(size_t)(rbase >> 2) * D_ + t * H_] = o;
    }
}

// ---------------------------------------------------------------------------
// Kernel 1 (m97 structure, proven): used when ws only fits nz=1.
// ---------------------------------------------------------------------------
__global__ __launch_bounds__(256) void gemm1f_k(
    const unsigned short* __restrict__ Aq,
    const unsigned short* __restrict__ Bq,
    unsigned short* __restrict__ P, int kk) {
  __shared__ unsigned short As[128 * 32];
  __shared__ unsigned short Bs[128 * 32];
  const int r0 = blockIdx.x * 128;
  const int t0 = blockIdx.y * 128;
  const int z  = blockIdx.z;
  const int kbeg = z * kk, kend = kbeg + kk;
  const int tid  = threadIdx.x;
  const int lane = tid & 63, wave = tid >> 6;
  const int wr = wave >> 1, wc = wave & 1;
  const int fr = lane & 15, fq = lane >> 4;
  const int l4 = lane >> 2, lb = lane & 3;
  unsigned short* __restrict__ Pz = P + (size_t)z * MTT_E;

  f32x4 acc[4][4];
  #pragma unroll
  for (int m = 0; m < 4; ++m)
    #pragma unroll
    for (int n = 0; n < 4; ++n) acc[m][n] = (f32x4){0.f, 0.f, 0.f, 0.f};

  for (int k0 = kbeg; k0 < kend; k0 += 32) {
    __syncthreads();
    #pragma unroll
    for (int c = 0; c < 2; ++c) {
      const int ch  = wave * 2 + c;
      const int row = ch * 16 + l4;
      __builtin_amdgcn_global_load_lds(
          (const AS1 void*)(Aq + (size_t)(r0 + row) * D_ + k0 + lb * 8),
          (AS3 void*)(As + ch * 512), 16, 0, 0);
      __builtin_amdgcn_global_load_lds(
          (const AS1 void*)(Bq + (size_t)(t0 + row) * D_ + k0 + lb * 8),
          (AS3 void*)(Bs + ch * 512), 16, 0, 0);
    }
    __syncthreads();
    bf16x8 af[4], bf[4];
    #pragma unroll
    for (int m = 0; m < 4; ++m)
      af[m] = *(const bf16x8*)&As[(wr * 64 + m * 16 + fr) * 32 + fq * 8];
    #pragma unroll
    for (int n = 0; n < 4; ++n)
      bf[n] = *(const bf16x8*)&Bs[(wc * 64 + n * 16 + fr) * 32 + fq * 8];
    #pragma unroll
    for (int m = 0; m < 4; ++m)
      #pragma unroll
      for (int n = 0; n < 4; ++n)
        acc[m][n] = __builtin_amdgcn_mfma_f32_16x16x32_bf16(af[m], bf[n], acc[m][n], 0, 0, 0);
  }
  #pragma unroll
  for (int m = 0; m < 4; ++m)
    #pragma unroll
    for (int n = 0; n < 4; ++n) {
      const int rbase = r0 + wr * 64 + m * 16 + fq * 4;
      const int t = t0 + wc * 64 + n * 16 + fr;
      ushort4 o;
      o.x = f2bf(acc[m][n][0]); o.y = f2bf(acc[m][n][1]);
      o.z = f2bf(acc[m][n][2]); o.w = f2bf(acc[m][n][3]);
      *(ushort4*)&Pz[(size_t)(rbase >> 2) * D_ + t * H_] = o;
    }
}

// ---------------------------------------------------------------------------
// Fused reduce+gather, LDS-staged (proven round-8):
// per block (one e-row): stream-sum nz partials coalesced into a 16KB LDS
// row (fp32 sum, bf16 round), then gather 8B chunks into GT.
// ---------------------------------------------------------------------------
__global__ __launch_bounds__(256) void rgather_k(
    const unsigned short* __restrict__ P, const int* __restrict__ x,
    unsigned short* __restrict__ GT, int nz) {
  __shared__ int toks[B_ * T_];          // 16 KB
  __shared__ unsigned short row[D_];     // 16 KB
  const int tid = threadIdx.x;
  #pragma unroll
  for (int c = 0; c < 16; ++c) toks[c * 256 + tid] = x[c * 256 + tid];

  const int e = blockIdx.x;
  const unsigned short* prow = P + (size_t)e * D_;

  float s[8][4];
  #pragma unroll
  for (int i = 0; i < 8; ++i) { s[i][0] = s[i][1] = s[i][2] = s[i][3] = 0.f; }
  for (int z = 0; z < nz; ++z) {
    const unsigned short* pz = prow + (size_t)z * MTT_E;
    #pragma unroll
    for (int i = 0; i < 8; ++i) {
      const ushort4 v = *(const ushort4*)(pz + (size_t)(i * 256 + tid) * 4);
      s[i][0] += bf2f(v.x); s[i][1] += bf2f(v.y);
      s[i][2] += bf2f(v.z); s[i][3] += bf2f(v.w);
    }
  }
  #pragma unroll
  for (int i = 0; i < 8; ++i) {
    ushort4 o;
    o.x = f2bf(s[i][0]); o.y = f2bf(s[i][1]);
    o.z = f2bf(s[i][2]); o.w = f2bf(s[i][3]);
    *(ushort4*)&row[(i * 256 + tid) * 4] = o;
  }
  __syncthreads();

  const int lane = tid & 63, wave = tid >> 6;
  #pragma unroll
  for (int bb = 0; bb < 2; ++bb) {
    const int b = wave * 2 + bb;
    unsigned short* grow = GT + ((size_t)b * NE_ + e) * K3;
    const int* tb = toks + b * T_;
    #pragma unroll
    for (int r = 0; r < 8; ++r) {
      const int j = r * 64 + lane;
      const uint2 v = *(const uint2*)&row[tb[j] * H_];
      *(uint2*)(grow + j * H_) = v;
    }
  }
}

// ---------------------------------------------------------------------------
// Kernel 3 (dense): y[b][i][e] = sum_k att[b,i,k] * GT[b,e,k] + pb[e]
// ---------------------------------------------------------------------------
__global__ __launch_bounds__(256) void gemm3f_k(
    const unsigned short* __restrict__ att,
    const unsigned short* __restrict__ GT,
    const float* __restrict__ bias,
    float* __restrict__ y) {
  __shared__ unsigned short As[128 * 32];
  __shared__ unsigned short Bs[64 * 32];
  const int b  = blockIdx.z;
  const int i0 = blockIdx.x * 128;
  const int e0 = blockIdx.y * 64;
  const int tid  = threadIdx.x;
  const int lane = tid & 63, wave = tid >> 6;
  const int wr = wave >> 1, wc = wave & 1;
  const int fr = lane & 15, fq = lane >> 4;

  f32x4 acc[4][2];
  #pragma unroll
  for (int m = 0; m < 4; ++m)
    #pragma unroll
    for (int n = 0; n < 2; ++n) acc[m][n] = (f32x4){0.f, 0.f, 0.f, 0.f};

  const unsigned short* aB = att + (size_t)(b * T_ + i0) * K3;
  const unsigned short* bB = GT + ((size_t)b * NE_ + e0) * K3;

  for (int k0 = 0; k0 < K3; k0 += 32) {
    __syncthreads();
    #pragma unroll
    for (int rdi = 0; rdi < 2; ++rdi) {
      const int q = rdi * 256 + tid;
      const int row = q >> 2, koff = (q & 3) * 8;
      __builtin_amdgcn_global_load_lds(
          (const AS1 void*)(aB + (size_t)row * K3 + k0 + koff),
          (AS3 void*)(As + q * 8), 16, 0, 0);
    }
    {
      const int q = tid;
      const int row = q >> 2, koff = (q & 3) * 8;
      __builtin_amdgcn_global_load_lds(
          (const AS1 void*)(bB + (size_t)row * K3 + k0 + koff),
          (AS3 void*)(Bs + q * 8), 16, 0, 0);
    }
    __syncthreads();
    bf16x8 af[4], bf[2];
    #pragma unroll
    for (int m = 0; m < 4; ++m)
      af[m] = *(const bf16x8*)&As[(wr * 64 + m * 16 + fr) * 32 + fq * 8];
    #pragma unroll
    for (int n = 0; n < 2; ++n)
      bf[n] = *(const bf16x8*)&Bs[(wc * 32 + n * 16 + fr) * 32 + fq * 8];
    #pragma unroll
    for (int m = 0; m < 4; ++m)
      #pragma unroll
      for (int n = 0; n < 2; ++n)
        acc[m][n] = __builtin_amdgcn_mfma_f32_16x16x32_bf16(af[m], bf[n], acc[m][n], 0, 0, 0);
  }

  #pragma unroll
  for (int m = 0; m < 4; ++m)
    #pragma unroll
    for (int n = 0; n < 2; ++n) {
      const int i = i0 + wr * 64 + m * 16 + fq * 4;
      const int e = e0 + wc * 32 + n * 16 + fr;
      const float be = bias[e];
      #pragma unroll
      for (int g = 0; g < 4; ++g)
        y[(size_t)(b * T_ + i + g) * NE_ + e] = acc[m][n][g] + be;
    }
}

// ---------------------------------------------------------------------------
// Kernel 2: att[b][i][j*4+h] = softmax_j(cooc[t_i, t_j, h]) + eye  (bf16)
// ---------------------------------------------------------------------------
__global__ __launch_bounds__(64) void softmax_k(
    const int* __restrict__ x, const float* __restrict__ cooc,
    unsigned short* __restrict__ att) {
  const int bi = blockIdx.x;
  const int b = bi >> 9, i = bi & (T_ - 1);
  const int lane = threadIdx.x;
  const int ti = x[b * T_ + i];
  const float* crow = cooc + (size_t)ti * D_;

  float w[8][4];
  #pragma unroll
  for (int r = 0; r < 8; ++r) {
    const int j = lane + r * 64;
    const int tj = x[b * T_ + j];
    const float4 v = *(const float4*)(crow + (size_t)tj * H_);
    w[r][0] = v.x; w[r][1] = v.y; w[r][2] = v.z; w[r][3] = v.w;
  }
  float m[4] = {-1e30f, -1e30f, -1e30f, -1e30f};
  #pragma unroll
  for (int r = 0; r < 8; ++r)
    #pragma unroll
    for (int h = 0; h < 4; ++h) m[h] = fmaxf(m[h], w[r][h]);
  #pragma unroll
  for (int off = 32; off > 0; off >>= 1)
    #pragma unroll
    for (int h = 0; h < 4; ++h) m[h] = fmaxf(m[h], __shfl_xor(m[h], off));
  float s[4] = {0.f, 0.f, 0.f, 0.f};
  #pragma unroll
  for (int r = 0; r < 8; ++r)
    #pragma unroll
    for (int h = 0; h < 4; ++h) { w[r][h] = __expf(w[r][h] - m[h]); s[h] += w[r][h]; }
  #pragma unroll
  for (int off = 32; off > 0; off >>= 1)
    #pragma unroll
    for (int h = 0; h < 4; ++h) s[h] += __shfl_xor(s[h], off);
  float inv[4];
  #pragma unroll
  for (int h = 0; h < 4; ++h) inv[h] = 1.f / s[h];

  unsigned short* arow = att + (size_t)(b * T_ + i) * (T_ * H_);
  #pragma unroll
  for (int r = 0; r < 8; ++r) {
    const int j = lane + r * 64;
    const float d = (j == i) ? 1.f : 0.f;
    ushort4 o;
    o.x = f2bf(w[r][0] * inv[0] + d);
    o.y = f2bf(w[r][1] * inv[1] + d);
    o.z = f2bf(w[r][2] * inv[2] + d);
    o.w = f2bf(w[r][3] * inv[3] + d);
    *(ushort4*)(arow + (size_t)j * H_) = o;
  }
}

// ---------------------------------------------------------------------------
// Round-1 fallback kernels (tiny ws)
// ---------------------------------------------------------------------------
__global__ __launch_bounds__(256) void gemm1_k(
    const float* __restrict__ pw, const float* __restrict__ cooc,
    unsigned short* __restrict__ mtT) {
  __shared__ unsigned short As[128 * 32];
  __shared__ unsigned short Bs[64 * 32];
  const int h  = blockIdx.z;
  const int e0 = blockIdx.x * 128;
  const int t0 = blockIdx.y * 64;
  const int tid  = threadIdx.x;
  const int lane = tid & 63, wave = tid >> 6;
  const int wr = wave >> 1, wc = wave & 1;
  const int fr = lane & 15, fq = lane >> 4;

  f32x4 acc[4][2];
  #pragma unroll
  for (int m = 0; m < 4; ++m)
    #pragma unroll
    for (int n = 0; n < 2; ++n) acc[m][n] = (f32x4){0.f, 0.f, 0.f, 0.f};

  const float* aB = pw + (size_t)e0 * PWROW + (size_t)h * D_;
  const float* bB = cooc + (size_t)t0 * D_;

  for (int k0 = 0; k0 < D_; k0 += 32) {
    __syncthreads();
    #pragma unroll
    for (int c = 0; c < 4; ++c) {
      const int fe = (c * 256 + tid) * 4;
      const int row = fe >> 5, k = fe & 31;
      const float4 v = *(const float4*)(aB + (size_t)row * PWROW + k0 + k);
      ushort4 o; o.x = f2bf(v.x); o.y = f2bf(v.y); o.z = f2bf(v.z); o.w = f2bf(v.w);
      *(ushort4*)&As[fe] = o;
    }
    #pragma unroll
    for (int c = 0; c < 2; ++c) {
      const int fe = (c * 256 + tid) * 4;
      const int row = fe >> 5, k = fe & 31;
      const float4 v = *(const float4*)(bB + (size_t)row * D_ + k0 + k);
      ushort4 o; o.x = f2bf(v.x); o.y = f2bf(v.y); o.z = f2bf(v.z); o.w = f2bf(v.w);
      *(ushort4*)&Bs[fe] = o;
    }
    __syncthreads();
    bf16x8 af[4], bf[2];
    #pragma unroll
    for (int m = 0; m < 4; ++m)
      af[m] = *(const bf16x8*)&As[(wr * 64 + m * 16 + fr) * 32 + fq * 8];
    #pragma unroll
    for (int n = 0; n < 2; ++n)
      bf[n] = *(const bf16x8*)&Bs[(wc * 32 + n * 16 + fr) * 32 + fq * 8];
    #pragma unroll
    for (int m = 0; m < 4; ++m)
      #pragma unroll
      for (int n = 0; n < 2; ++n)
        acc[m][n] = __builtin_amdgcn_mfma_f32_16x16x32_bf16(af[m], bf[n], acc[m][n], 0, 0, 0);
  }
  #pragma unroll
  for (int m = 0; m < 4; ++m)
    #pragma unroll
    for (int n = 0; n < 2; ++n) {
      const int e = e0 + wr * 64 + m * 16 + fq * 4;
      const int t = t0 + wc * 32 + n * 16 + fr;
      #pragma unroll
      for (int g = 0; g < 4; ++g)
        mtT[(size_t)(e + g) * D_ + t * H_ + h] = f2bf(acc[m][n][g]);
    }
}

__global__ __launch_bounds__(256) void gemm3_k(
    const unsigned short* __restrict__ att, const unsigned short* __restrict__ mtT,
    const int* __restrict__ x, const float* __restrict__ bias,
    float* __restrict__ y) {
  __shared__ unsigned short As[64 * 32];
  __shared__ unsigned short Bs[128 * 32];
  const int b  = blockIdx.z;
  const int i0 = blockIdx.x * 64;
  const int e0 = blockIdx.y * 128;
  const int tid  = threadIdx.x;
  const int lane = tid & 63, wave = tid >> 6;
  const int wr = wave >> 1, wc = wave & 1;
  const int fr = lane & 15, fq = lane >> 4;

  f32x4 acc[2][4];
  #pragma unroll
  for (int m = 0; m < 2; ++m)
    #pragma unroll
    for (int n = 0; n < 4; ++n) acc[m][n] = (f32x4){0.f, 0.f, 0.f, 0.f};

  const unsigned short* aB = att + (size_t)(b * T_ + i0) * (T_ * H_);

  for (int ks = 0; ks < 64; ++ks) {
    const int k0 = ks * 32;
    __syncthreads();
    {
      const int fe = tid * 8;
      const int row = fe >> 5, k = fe & 31;
      const uint4 v = *(const uint4*)(aB + (size_t)row * (T_ * H_) + k0 + k);
      *(uint4*)&As[fe] = v;
    }
    #pragma unroll
    for (int c = 0; c < 4; ++c) {
      const int q = c * 256 + tid;
      const int n = q >> 3, j8 = q & 7;
      const int tj = x[b * T_ + ks * 8 + j8];
      const uint2 v = *(const uint2*)(mtT + (size_t)(e0 + n) * D_ + tj * H_);
      *(uint2*)&Bs[n * 32 + j8 * 4] = v;
    }
    __syncthreads();
    bf16x8 af[2], bf[4];
    #pragma unroll
    for (int m = 0; m < 2; ++m)
      af[m] = *(const bf16x8*)&As[(wr * 32 + m * 16 + fr) * 32 + fq * 8];
    #pragma unroll
    for (int n = 0; n < 4; ++n)
      bf[n] = *(const bf16x8*)&Bs[(wc * 64 + n * 16 + fr) * 32 + fq * 8];
    #pragma unroll
    for (int m = 0; m < 2; ++m)
      #pragma unroll
      for (int n = 0; n < 4; ++n)
        acc[m][n] = __builtin_amdgcn_mfma_f32_16x16x32_bf16(af[m], bf[n], acc[m][n], 0, 0, 0);
  }
  #pragma unroll
  for (int m = 0; m < 2; ++m)
    #pragma unroll
    for (int n = 0; n < 4; ++n) {
      const int i = i0 + wr * 32 + m * 16 + fq * 4;
      const int e = e0 + wc * 64 + n * 16 + fr;
      const float be = bias[e];
      #pragma unroll
      for (int g = 0; g < 4; ++g)
        y[(size_t)(b * T_ + i + g) * NE_ + e] = acc[m][n][g] + be;
    }
}

// ---------------------------------------------------------------------------
extern "C" void kernel_launch(void* const* d_in, const int* in_sizes, int n_in,
                              void* d_out, int out_size, void* d_ws, size_t ws_size,
                              hipStream_t stream) {
  const int*   x    = (const int*)d_in[0];
  const float* cooc = (const float*)d_in[1];
  const float* pw   = (const float*)d_in[2];
  const float* pb   = (const float*)d_in[3];
  float* y = (float*)d_out;

  const size_t BQ_E = (size_t)V_ * D_;           // 16777216
  const size_t AQ_E = (size_t)M1 * D_;           // 25165824

  unsigned short* mtT = (unsigned short*)d_ws;   // == P0
  auto need = [&](int c) { return ((size_t)c * MTT_E + BQ_E + AQ_E) * 2; };

  int nz = 0;
  if      (ws_size >= need(2)) nz = 2;   // gemm1r path (768 blocks = 3/CU)
  else if (ws_size >= need(1)) nz = 1;   // gemm1f path

  if (nz >= 1) {
    unsigned short* Bq  = mtT + (size_t)nz * MTT_E;
    unsigned short* Aq  = Bq + BQ_E;
    unsigned short* GT  = Bq;   // alias: valid after gemm1
    unsigned short* att = Aq;   // alias: valid after gemm1
    hipLaunchKernelGGL(cvtAB_k, dim3(2048), dim3(256), 0, stream,
                       cooc, pw, Bq, (int)(BQ_E / 4), (int)((BQ_E + AQ_E) / 4));
    if (nz == 2)
      hipLaunchKernelGGL(gemm1r_k, dim3(M1 / 128, V_ / 128, 2), dim3(256), 0,
                         stream, Aq, Bq, mtT, D_ / 2);
    else
      hipLaunchKernelGGL(gemm1f_k, dim3(M1 / 128, V_ / 128, 1), dim3(256), 0,
                         stream, Aq, Bq, mtT, D_);
    hipLaunchKernelGGL(softmax_k, dim3(B_ * T_), dim3(64), 0, stream, x, cooc, att);
    hipLaunchKernelGGL(rgather_k, dim3(NE_), dim3(256), 0, stream, mtT, x, GT, nz);
    hipLaunchKernelGGL(gemm3f_k, dim3(T_ / 128, NE_ / 64, B_), dim3(256), 0, stream,
                       att, GT, pb, y);
  } else {
    unsigned short* att = mtT + MTT_E;
    hipLaunchKernelGGL(gemm1_k, dim3(NE_ / 128, V_ / 64, H_), dim3(256), 0, stream,
                       pw, cooc, mtT);
    hipLaunchKernelGGL(softmax_k, dim3(B_ * T_), dim3(64), 0, stream, x, cooc, att);
    hipLaunchKernelGGL(gemm3_k, dim3(T_ / 64, NE_ / 128, B_), dim3(256), 0, stream,
                       att, mtT, x, pb, y);
  }
}